// Round 1
// baseline (75.532 us; speedup 1.0000x reference)
//
#include <hip/hip_runtime.h>

// Problem constants (fixed by the reference):
constexpr int BATCH = 256;
constexpr int CH    = 512;
constexpr int KS    = 5;
constexpr int PAD   = (KS - 1) / 2;  // 'same' padding = 2

// One block per batch, one thread per channel/row.
// scores[c,d] = qh[c]*kh[d]  (rank-1), softmax over d, dot with vh.
__global__ __launch_bounds__(CH, 2) void attn1d_kernel(
    const float* __restrict__ q, const float* __restrict__ k, const float* __restrict__ v,
    const float* __restrict__ wq, const float* __restrict__ wk, const float* __restrict__ wv,
    float* __restrict__ out)
{
    __shared__ float sq[CH], sk[CH], sv[CH];   // raw input rows
    __shared__ float kh[CH], vh[CH];           // conv outputs needed by all threads
    __shared__ float wred_max[8], wred_min[8];
    __shared__ float s_kmax, s_kmin;

    const int b = blockIdx.x;
    const int t = threadIdx.x;

    // Stage input rows (coalesced dword loads, 2 KB per array).
    sq[t] = q[b * CH + t];
    sk[t] = k[b * CH + t];
    sv[t] = v[b * CH + t];

    // Conv weights: uniform across threads -> compiler scalarizes; L1-cached.
    float w_q[KS], w_k[KS], w_v[KS];
#pragma unroll
    for (int j = 0; j < KS; ++j) { w_q[j] = wq[j]; w_k[j] = wk[j]; w_v[j] = wv[j]; }
    __syncthreads();

    // 'same' cross-correlation (XLA conv does NOT flip the kernel), zero-padded.
    float aq = 0.f, ak = 0.f, av = 0.f;
#pragma unroll
    for (int j = 0; j < KS; ++j) {
        const int idx = t + j - PAD;
        if (idx >= 0 && idx < CH) {
            aq = fmaf(sq[idx], w_q[j], aq);
            ak = fmaf(sk[idx], w_k[j], ak);
            av = fmaf(sv[idx], w_v[j], av);
        }
    }
    kh[t] = ak;
    vh[t] = av;

    // Block max/min of kh -> exact per-row score max for stable softmax.
    float lmax = ak, lmin = ak;
#pragma unroll
    for (int off = 32; off > 0; off >>= 1) {
        lmax = fmaxf(lmax, __shfl_down(lmax, off, 64));
        lmin = fminf(lmin, __shfl_down(lmin, off, 64));
    }
    const int wave = t >> 6;
    if ((t & 63) == 0) { wred_max[wave] = lmax; wred_min[wave] = lmin; }
    __syncthreads();  // also publishes kh/vh
    if (t == 0) {
        float m = wred_max[0], n = wred_min[0];
#pragma unroll
        for (int i = 1; i < 8; ++i) { m = fmaxf(m, wred_max[i]); n = fminf(n, wred_min[i]); }
        s_kmax = m; s_kmin = n;
    }
    __syncthreads();

    // Row max of qh[t]*kh[d] over d is qh*max(kh) or qh*min(kh) by sign.
    const float qc = aq;
    const float m = (qc >= 0.f) ? qc * s_kmax : qc * s_kmin;

    // Online numer/denom. kh/vh read as float4 LDS broadcasts (all lanes same
    // address -> no bank conflicts). 128 iters x (4 exp + 8 fma).
    float den = 0.f, num = 0.f;
    const float4* kh4 = (const float4*)kh;
    const float4* vh4 = (const float4*)vh;
#pragma unroll 4
    for (int d4 = 0; d4 < CH / 4; ++d4) {
        const float4 kk = kh4[d4];
        const float4 vv = vh4[d4];
        const float e0 = __expf(fmaf(qc, kk.x, -m));
        const float e1 = __expf(fmaf(qc, kk.y, -m));
        const float e2 = __expf(fmaf(qc, kk.z, -m));
        const float e3 = __expf(fmaf(qc, kk.w, -m));
        den += (e0 + e1) + (e2 + e3);
        num = fmaf(e0, vv.x, num);
        num = fmaf(e1, vv.y, num);
        num = fmaf(e2, vv.z, num);
        num = fmaf(e3, vv.w, num);
    }

    out[b * CH + t] = num / den;
}

extern "C" void kernel_launch(void* const* d_in, const int* in_sizes, int n_in,
                              void* d_out, int out_size, void* d_ws, size_t ws_size,
                              hipStream_t stream) {
    const float* q  = (const float*)d_in[0];
    const float* k  = (const float*)d_in[1];
    const float* v  = (const float*)d_in[2];
    const float* wq = (const float*)d_in[3];
    const float* wk = (const float*)d_in[4];
    const float* wv = (const float*)d_in[5];
    float* out = (float*)d_out;

    attn1d_kernel<<<BATCH, CH, 0, stream>>>(q, k, v, wq, wk, wv, out);
}